// Round 1
// baseline (29.966 us; speedup 1.0000x reference)
//
#include <hip/hip_runtime.h>
#include <math.h>

#define NOUT 64
#define NIN  64
#define HH   32
#define WW   32
#define PADH 34
#define PADW 34

#define CSPLIT 4
#define CPER   (NIN / CSPLIT)      // 16
#define ROWSPB 8
#define TILES  (HH / ROWSPB)       // 4

// ---------- prep: transpose + zero-pad x[1][32][32][64] -> xt[64][34][34] ----------
__global__ __launch_bounds__(256) void xpose_kernel(const float* __restrict__ x,
                                                    float* __restrict__ xt) {
    int idx = blockIdx.x * 256 + threadIdx.x;
    const int total = NIN * PADH * PADW;
    if (idx >= total) return;
    int jj = idx % PADW;
    int t  = idx / PADW;
    int ii = t % PADH;
    int c  = t / PADH;
    float v = 0.0f;
    if (ii >= 1 && ii <= HH && jj >= 1 && jj <= WW)
        v = x[((ii - 1) * WW + (jj - 1)) * NIN + c];
    xt[idx] = v;
}

// ---------- rational eval: P5(x) / (1 + |x*H3(x)|) ----------
__device__ __forceinline__ void rat_acc(float x, const float* __restrict__ A,
                                        const float* __restrict__ B, float& acc) {
    float p = A[5];
    p = fmaf(p, x, A[4]);
    p = fmaf(p, x, A[3]);
    p = fmaf(p, x, A[2]);
    p = fmaf(p, x, A[1]);
    p = fmaf(p, x, A[0]);
    float q = B[3];
    q = fmaf(q, x, B[2]);
    q = fmaf(q, x, B[1]);
    q = fmaf(q, x, B[0]);
    float den = 1.0f + fabsf(x * q);
    acc = fmaf(p, __builtin_amdgcn_rcpf(den), acc);
}

// ---------- main kernel (planar padded xt path) ----------
__global__ __launch_bounds__(256) void kan_main(const float* __restrict__ xt,
                                                const float* __restrict__ wn,
                                                const float* __restrict__ wd,
                                                float* __restrict__ out) {
    int bid = blockIdx.x;
    int s = bid & (CSPLIT - 1);
    int t = (bid >> 2) & (TILES - 1);
    int f = bid >> 4;

    int lid = threadIdx.x;
    int j = lid & (WW - 1);
    int r = lid >> 5;
    int i = t * ROWSPB + r;
    int c0 = s * CPER;

    const float* xb  = xt + c0 * (PADH * PADW) + i * PADW + j;
    const float* wnb = wn + (f * NIN + c0) * 9 * 6;
    const float* wdb = wd + (f * NIN + c0) * 9 * 4;

    float acc = 0.0f;
    for (int c = 0; c < CPER; ++c) {
        const float* xp = xb + c * (PADH * PADW);
        float xv[9];
#pragma unroll
        for (int a = 0; a < 3; ++a)
#pragma unroll
            for (int b = 0; b < 3; ++b)
                xv[a * 3 + b] = xp[a * PADW + b];
        const float* wnc = wnb + c * 54;
        const float* wdc = wdb + c * 36;
#pragma unroll
        for (int ab = 0; ab < 9; ++ab)
            rat_acc(xv[ab], wnc + ab * 6, wdc + ab * 4, acc);
    }
    atomicAdd(&out[f * (HH * WW) + i * WW + j], acc);
}

// ---------- fallback (no workspace): gather x directly with bounds checks ----------
__global__ __launch_bounds__(256) void kan_fallback(const float* __restrict__ x,
                                                    const float* __restrict__ wn,
                                                    const float* __restrict__ wd,
                                                    float* __restrict__ out) {
    int bid = blockIdx.x;
    int s = bid & (CSPLIT - 1);
    int t = (bid >> 2) & (TILES - 1);
    int f = bid >> 4;

    int lid = threadIdx.x;
    int j = lid & (WW - 1);
    int r = lid >> 5;
    int i = t * ROWSPB + r;
    int c0 = s * CPER;

    const float* wnb = wn + (f * NIN + c0) * 9 * 6;
    const float* wdb = wd + (f * NIN + c0) * 9 * 4;

    float acc = 0.0f;
    for (int c = 0; c < CPER; ++c) {
        float xv[9];
#pragma unroll
        for (int a = 0; a < 3; ++a)
#pragma unroll
            for (int b = 0; b < 3; ++b) {
                int ii = i + a - 1, jj = j + b - 1;
                bool inb = (ii >= 0) && (ii < HH) && (jj >= 0) && (jj < WW);
                xv[a * 3 + b] = inb ? x[(ii * WW + jj) * NIN + (c0 + c)] : 0.0f;
            }
        const float* wnc = wnb + c * 54;
        const float* wdc = wdb + c * 36;
#pragma unroll
        for (int ab = 0; ab < 9; ++ab)
            rat_acc(xv[ab], wnc + ab * 6, wdc + ab * 4, acc);
    }
    atomicAdd(&out[f * (HH * WW) + i * WW + j], acc);
}

extern "C" void kernel_launch(void* const* d_in, const int* in_sizes, int n_in,
                              void* d_out, int out_size, void* d_ws, size_t ws_size,
                              hipStream_t stream) {
    const float* x  = (const float*)d_in[0];
    const float* wn = (const float*)d_in[1];
    const float* wd = (const float*)d_in[2];
    float* out = (float*)d_out;

    hipMemsetAsync(d_out, 0, (size_t)out_size * sizeof(float), stream);

    const size_t xt_bytes = (size_t)NIN * PADH * PADW * sizeof(float);
    const int nblocks = NOUT * TILES * CSPLIT;  // 1024

    if (ws_size >= xt_bytes) {
        float* xt = (float*)d_ws;
        const int total = NIN * PADH * PADW;
        xpose_kernel<<<(total + 255) / 256, 256, 0, stream>>>(x, xt);
        kan_main<<<nblocks, 256, 0, stream>>>(xt, wn, wd, out);
    } else {
        kan_fallback<<<nblocks, 256, 0, stream>>>(x, wn, wd, out);
    }
}